// Round 3
// baseline (384.499 us; speedup 1.0000x reference)
//
#include <hip/hip_runtime.h>
#include <hip/hip_bf16.h>
#include <math.h>

#define T_SEQ   2048
#define D_MOD   1024
#define N_HEADS 16
#define HEAD_DIM 64
#define B_BATCH 2
#define M_ROWS  (B_BATCH * T_SEQ)   // 4096

typedef unsigned short u16;
typedef __attribute__((ext_vector_type(8))) short short8;
typedef __attribute__((ext_vector_type(4))) float floatx4;

__device__ inline floatx4 mfma16(short8 a, short8 b, floatx4 c) {
  return __builtin_amdgcn_mfma_f32_16x16x32_bf16(a, b, c, 0, 0, 0);
}

__device__ inline u16 f2bf(float f) {
  __hip_bfloat16 h = __float2bfloat16(f);   // RTN
  return __builtin_bit_cast(u16, h);
}

// async global -> LDS, 16B per lane; dest = uniform base + lane*16
__device__ inline void gload16(const void* g, void* s) {
  __builtin_amdgcn_global_load_lds(
      (const __attribute__((address_space(1))) void*)g,
      (__attribute__((address_space(3))) void*)s, 16, 0, 0);
}

// ---------------------------------------------------------------- fused casts
__global__ void cast_all_kernel(const float* __restrict__ x,
                                const float* __restrict__ Wq, const float* __restrict__ Wk,
                                const float* __restrict__ Wv, const float* __restrict__ Wo,
                                u16* __restrict__ Xb, u16* __restrict__ Wqb, u16* __restrict__ Wkb,
                                u16* __restrict__ Wvb, u16* __restrict__ Wob) {
  size_t i4 = ((size_t)blockIdx.x * 256 + threadIdx.x) * 4;
  size_t seg = i4 >> 20;
  const float* src; u16* dst; size_t off;
  if (seg < 4)       { src = x;  dst = Xb;  off = i4; }
  else if (seg == 4) { src = Wq; dst = Wqb; off = i4 - ((size_t)4 << 20); }
  else if (seg == 5) { src = Wk; dst = Wkb; off = i4 - ((size_t)5 << 20); }
  else if (seg == 6) { src = Wv; dst = Wvb; off = i4 - ((size_t)6 << 20); }
  else               { src = Wo; dst = Wob; off = i4 - ((size_t)7 << 20); }
  float4 v = *(const float4*)(src + off);
  ushort4 o;
  o.x = f2bf(v.x); o.y = f2bf(v.y); o.z = f2bf(v.z); o.w = f2bf(v.w);
  *(ushort4*)(dst + off) = o;
}

// ---------------------------------------------------------------- rope table
__global__ void rope_table_kernel(float* __restrict__ cosT, float* __restrict__ sinT) {
  int tid = blockIdx.x * blockDim.x + threadIdx.x;   // T*32
  int t = tid >> 5, j = tid & 31;
  double inv = pow(10000.0, -((double)(2 * j) / 64.0));
  double a = (double)t * inv;
  cosT[tid] = (float)cos(a);
  sinT[tid] = (float)sin(a);
}

// ---------------------------------------------------------------- GEMM: C[M,N] = A[M,K] * W[N,K]^T + bias
// 128x128 tile, BK=32, double-buffered LDS via global_load_lds(16B), 4 waves (2x2).
// DO_ROPE: z<2 -> fused RoPE epilogue (Q,K); z==2 -> V^T epilogue (writes [B,H,64,T]).
template<int OUT_BF16, int DO_ROPE>
__global__ __launch_bounds__(256) void gemm128_kernel(
    const u16* __restrict__ A,
    const u16* __restrict__ W0, const u16* __restrict__ W1, const u16* __restrict__ W2,
    const float* __restrict__ b0, const float* __restrict__ b1, const float* __restrict__ b2,
    void* __restrict__ C0, void* __restrict__ C1, void* __restrict__ C2,
    const float* __restrict__ cosT, const float* __restrict__ sinT) {
  const int z = blockIdx.z;
  const u16*  W    = (z == 0) ? W0 : (z == 1 ? W1 : W2);
  const float* bias = (z == 0) ? b0 : (z == 1 ? b1 : b2);
  void*       C    = (z == 0) ? C0 : (z == 1 ? C1 : C2);
  const int K = D_MOD, N = D_MOD;

  __shared__ __align__(16) char smem[34816];   // 2x(8K lA)+2x(8K lB) = 32K; pt = 34816
  u16* lA0 = (u16*)smem;                 // [128*32]
  u16* lA1 = (u16*)(smem + 8192);
  u16* lB0 = (u16*)(smem + 16384);
  u16* lB1 = (u16*)(smem + 24576);

  const int tid = threadIdx.x;
  const int w = tid >> 6, l = tid & 63, g = l >> 4, ln = l & 15;
  const int wr = w >> 1, wc = w & 1;
  const int m0 = blockIdx.y * 128, n0 = blockIdx.x * 128;

  floatx4 acc[4][4];
#pragma unroll
  for (int mi = 0; mi < 4; ++mi)
#pragma unroll
    for (int ni = 0; ni < 4; ++ni) acc[mi][ni] = (floatx4){0.f, 0.f, 0.f, 0.f};

  auto stage = [&](u16* la, u16* lb, int kk) {
#pragma unroll
    for (int p = 0; p < 2; ++p) {
      int c = p * 256 + w * 64 + l;
      int r = c >> 2, cc = c & 3;
      gload16(A + (size_t)(m0 + r) * K + kk + cc * 8, la + (p * 256 + w * 64) * 8);
      gload16(W + (size_t)(n0 + r) * K + kk + cc * 8, lb + (p * 256 + w * 64) * 8);
    }
  };

  stage(lA0, lB0, 0);
  __syncthreads();
  for (int t = 0; t < K / 32; ++t) {
    u16* la = (t & 1) ? lA1 : lA0;
    u16* lb = (t & 1) ? lB1 : lB0;
    if (t + 1 < K / 32) stage((t & 1) ? lA0 : lA1, (t & 1) ? lB0 : lB1, (t + 1) * 32);
    short8 af[4], bf[4];
#pragma unroll
    for (int mi = 0; mi < 4; ++mi)
      af[mi] = *(const short8*)&la[(wr * 64 + mi * 16 + ln) * 32 + g * 8];
#pragma unroll
    for (int ni = 0; ni < 4; ++ni)
      bf[ni] = *(const short8*)&lb[(wc * 64 + ni * 16 + ln) * 32 + g * 8];
#pragma unroll
    for (int mi = 0; mi < 4; ++mi)
#pragma unroll
      for (int ni = 0; ni < 4; ++ni)
        acc[mi][ni] = mfma16(af[mi], bf[ni], acc[mi][ni]);
    __syncthreads();
  }

  float bv[4];
#pragma unroll
  for (int ni = 0; ni < 4; ++ni) bv[ni] = bias[n0 + wc * 64 + ni * 16 + ln];

  if (DO_ROPE && z == 2) {
    // ---- V^T epilogue: bounce C-tile through LDS, write Vt[B,H,64,T]
    u16* pt = (u16*)smem;   // [128][136] u16, row = n_local, col = m_local
#pragma unroll
    for (int mi = 0; mi < 4; ++mi)
#pragma unroll
      for (int ni = 0; ni < 4; ++ni)
#pragma unroll
        for (int r = 0; r < 4; ++r)
          pt[(wc * 64 + ni * 16 + ln) * 136 + wr * 64 + mi * 16 + g * 4 + r] =
              f2bf(acc[mi][ni][r] + bv[ni]);
    __syncthreads();
    u16* Vt = (u16*)C;
    const int b = m0 >> 11, tc0 = m0 & (T_SEQ - 1);
#pragma unroll
    for (int i = 0; i < 8; ++i) {
      const int c = tid + 256 * i;
      const int row = c >> 4, mc = c & 15;       // row: n_local 0..127, mc: 16B chunk
      const int n = n0 + row;
      const int hh = n >> 6, d = n & 63;
      short8 val = *(const short8*)&pt[row * 136 + mc * 8];
      *(short8*)(Vt + ((size_t)(b * N_HEADS + hh) * 64 + d) * T_SEQ + tc0 + mc * 8) = val;
    }
    return;
  }

#pragma unroll
  for (int mi = 0; mi < 4; ++mi) {
#pragma unroll
    for (int r = 0; r < 4; ++r) {
      const int m = m0 + wr * 64 + mi * 16 + g * 4 + r;
      if (DO_ROPE && z < 2) {
        const int t = m & (T_SEQ - 1);
#pragma unroll
        for (int ni = 0; ni < 2; ++ni) {
          const int j = ni * 16 + ln;
          float cv = cosT[t * 32 + j], sv = sinT[t * 32 + j];
          float v1 = acc[mi][ni][r] + bv[ni];
          float v2 = acc[mi][ni + 2][r] + bv[ni + 2];
          ((u16*)C)[(size_t)m * N + n0 + wc * 64 + j]      = f2bf(v1 * cv - v2 * sv);
          ((u16*)C)[(size_t)m * N + n0 + wc * 64 + j + 32] = f2bf(v1 * sv + v2 * cv);
        }
      } else {
#pragma unroll
        for (int ni = 0; ni < 4; ++ni) {
          float v = acc[mi][ni][r] + bv[ni];
          size_t idx = (size_t)m * N + n0 + wc * 64 + ni * 16 + ln;
          if (OUT_BF16) ((u16*)C)[idx] = f2bf(v);
          else          ((float*)C)[idx] = v;
        }
      }
    }
  }
}

// ---------------------------------------------------------------- flash attention v3 (causal)
// Barrier-free: 4 independent waves/block, 16 q-rows/wave, KVBLK=64.
// K and V^T fragments direct from global (L1/L2-resident); P via per-wave LDS slab.
__global__ __launch_bounds__(256) void flash3_kernel(const u16* __restrict__ Q, const u16* __restrict__ Kb,
                                                     const u16* __restrict__ Vt, u16* __restrict__ O) {
  __shared__ __align__(16) u16 pl[4][16 * 136];   // per-wave P slab, 17.4KB total

  const int tid = threadIdx.x;
  const int w = tid >> 6, l = tid & 63, g = l >> 4, ln = l & 15;

  // XCD-clustered mapping: xcd = orig%8 gets 4 consecutive bh (K+Vt ~2MB fits 4MB L2)
  const int orig = blockIdx.x;                    // 0..1023
  const int wg = (orig & 7) * 128 + (orig >> 3);
  const int bh = wg >> 5;                         // 0..31
  const int qg = wg & 31;                         // 0..31
  const int qt = qg * 4 + w;                      // 0..127 (per-wave q tile)
  const int q0 = qt * 16;
  const int b = bh >> 4, h = bh & 15;

  const u16* Qh = Q  + (size_t)b * T_SEQ * D_MOD + h * HEAD_DIM;
  const u16* Kh = Kb + (size_t)b * T_SEQ * D_MOD + h * HEAD_DIM;
  const u16* Vh = Vt + (size_t)bh * 64 * T_SEQ;   // rows d, stride T_SEQ
  u16* pb = pl[w];

  // Q fragments (16 rows x k64)
  short8 qf0, qf1;
  {
    const u16* qp = Qh + (size_t)(q0 + ln) * D_MOD;
    qf0 = *(const short8*)(qp + g * 8);
    qf1 = *(const short8*)(qp + 32 + g * 8);
  }

  floatx4 oacc[4];
#pragma unroll
  for (int db = 0; db < 4; ++db) oacc[db] = (floatx4){0.f, 0.f, 0.f, 0.f};
  float m_r[4] = {-INFINITY, -INFINITY, -INFINITY, -INFINITY};
  float l_r[4] = {0.f, 0.f, 0.f, 0.f};

  const int nkv = ((q0 + 15) >> 6) + 1;
  for (int kt = 0; kt < nkv; ++kt) {
    const int k0 = kt * 64;
    const bool lastt = (kt == nkv - 1);

    // ---- S = Q K^T, fragments straight from global
    float sv[4][4];
    __builtin_amdgcn_s_setprio(1);
#pragma unroll
    for (int nt = 0; nt < 4; ++nt) {
      const u16* kp = Kh + (size_t)(k0 + nt * 16 + ln) * D_MOD;
      short8 kf0 = *(const short8*)(kp + g * 8);
      short8 kf1 = *(const short8*)(kp + 32 + g * 8);
      floatx4 s = (floatx4){0.f, 0.f, 0.f, 0.f};
      s = mfma16(qf0, kf0, s);
      s = mfma16(qf1, kf1, s);
#pragma unroll
      for (int r = 0; r < 4; ++r) {
        float x = s[r] * 0.125f;
        if (lastt && (k0 + nt * 16 + ln) > (q0 + g * 4 + r)) x = -10000.0f;
        sv[nt][r] = x;
      }
    }
    __builtin_amdgcn_s_setprio(0);

    // ---- online softmax (k lives across 16 lanes + 4 nt)
#pragma unroll
    for (int r = 0; r < 4; ++r) {
      float mx = fmaxf(fmaxf(sv[0][r], sv[1][r]), fmaxf(sv[2][r], sv[3][r]));
      mx = fmaxf(mx, __shfl_xor(mx, 1));
      mx = fmaxf(mx, __shfl_xor(mx, 2));
      mx = fmaxf(mx, __shfl_xor(mx, 4));
      mx = fmaxf(mx, __shfl_xor(mx, 8));
      float mnew = fmaxf(m_r[r], mx);
      float alpha = __expf(m_r[r] - mnew);   // first tile: exp(-inf)=0
      float ssum = 0.f;
#pragma unroll
      for (int nt = 0; nt < 4; ++nt) {
        float pv = __expf(sv[nt][r] - mnew);
        sv[nt][r] = pv;
        ssum += pv;
      }
      ssum += __shfl_xor(ssum, 1);
      ssum += __shfl_xor(ssum, 2);
      ssum += __shfl_xor(ssum, 4);
      ssum += __shfl_xor(ssum, 8);
      l_r[r] = l_r[r] * alpha + ssum;
      m_r[r] = mnew;
#pragma unroll
      for (int db = 0; db < 4; ++db) oacc[db][r] *= alpha;
    }

    // ---- P -> bf16 -> per-wave LDS slab (intra-wave, no barrier)
#pragma unroll
    for (int nt = 0; nt < 4; ++nt)
#pragma unroll
      for (int r = 0; r < 4; ++r)
        pb[(g * 4 + r) * 136 + nt * 16 + ln] = f2bf(sv[nt][r]);

    short8 pa0 = *(const short8*)&pb[ln * 136 + g * 8];
    short8 pa1 = *(const short8*)&pb[ln * 136 + 32 + g * 8];

    // ---- O += P V  (V^T rows direct from global)
    __builtin_amdgcn_s_setprio(1);
#pragma unroll
    for (int db = 0; db < 4; ++db) {
      const u16* vp = Vh + (size_t)(db * 16 + ln) * T_SEQ + k0;
      short8 v0 = *(const short8*)(vp + g * 8);
      short8 v1 = *(const short8*)(vp + 32 + g * 8);
      oacc[db] = mfma16(pa0, v0, oacc[db]);
      oacc[db] = mfma16(pa1, v1, oacc[db]);
    }
    __builtin_amdgcn_s_setprio(0);
  }

  // ---- epilogue: O / l, store bf16 [B,T,D]
#pragma unroll
  for (int r = 0; r < 4; ++r) {
    float inv = 1.0f / l_r[r];
    const int q = q0 + g * 4 + r;
    u16* op = O + (size_t)b * T_SEQ * D_MOD + (size_t)q * D_MOD + h * HEAD_DIM;
#pragma unroll
    for (int db = 0; db < 4; ++db)
      op[db * 16 + ln] = f2bf(oacc[db][r] * inv);
  }
}

// ---------------------------------------------------------------- launch
extern "C" void kernel_launch(void* const* d_in, const int* in_sizes, int n_in,
                              void* d_out, int out_size, void* d_ws, size_t ws_size,
                              hipStream_t stream) {
  const float* x  = (const float*)d_in[0];
  const float* Wq = (const float*)d_in[2];
  const float* bq = (const float*)d_in[3];
  const float* Wk = (const float*)d_in[4];
  const float* bk = (const float*)d_in[5];
  const float* Wv = (const float*)d_in[6];
  const float* bv = (const float*)d_in[7];
  const float* Wo = (const float*)d_in[8];
  const float* bo = (const float*)d_in[9];
  float* out = (float*)d_out;

  char* ws = (char*)d_ws;
  const size_t MB = 1024 * 1024;
  u16* Xb   = (u16*)(ws + 0);          // 8 MB; dead after QKV gemm -> Ab reuses it
  u16* Ab   = (u16*)(ws + 0);
  u16* Wqb  = (u16*)(ws + 8 * MB);
  u16* Wkb  = (u16*)(ws + 10 * MB);
  u16* Wvb  = (u16*)(ws + 12 * MB);
  u16* Wob  = (u16*)(ws + 14 * MB);
  u16* Qb   = (u16*)(ws + 16 * MB);    // 8 MB
  u16* Kb   = (u16*)(ws + 24 * MB);    // 8 MB
  u16* Vt   = (u16*)(ws + 32 * MB);    // 16 MB  [B,H,64,T]
  float* cosT = (float*)(ws + 48 * MB);          // 256 KB
  float* sinT = (float*)(ws + 48 * MB + 256 * 1024);

  cast_all_kernel<<<8192, 256, 0, stream>>>(x, Wq, Wk, Wv, Wo, Xb, Wqb, Wkb, Wvb, Wob);
  rope_table_kernel<<<256, 256, 0, stream>>>(cosT, sinT);

  // fused Q/K/V projections: RoPE epilogue for z<2, V^T epilogue for z==2
  gemm128_kernel<1, 1><<<dim3(8, 32, 3), 256, 0, stream>>>(
      Xb, Wqb, Wkb, Wvb, bq, bk, bv, Qb, Kb, Vt, cosT, sinT);

  flash3_kernel<<<dim3(1024), 256, 0, stream>>>(Qb, Kb, Vt, Ab);

  gemm128_kernel<0, 0><<<dim3(8, 32, 1), 256, 0, stream>>>(
      Ab, Wob, Wob, Wob, bo, bo, bo, out, out, out, nullptr, nullptr);
}

// Round 5
// 235.481 us; speedup vs baseline: 1.6328x; 1.6328x over previous
//
#include <hip/hip_runtime.h>
#include <hip/hip_bf16.h>
#include <math.h>

#define T_SEQ   2048
#define D_MOD   1024
#define N_HEADS 16
#define HEAD_DIM 64
#define B_BATCH 2
#define M_ROWS  (B_BATCH * T_SEQ)   // 4096

typedef unsigned short u16;
typedef unsigned int u32;
typedef __attribute__((ext_vector_type(8))) short short8;
typedef __attribute__((ext_vector_type(4))) float floatx4;
typedef __attribute__((ext_vector_type(16))) float f32x16;
typedef __attribute__((ext_vector_type(4))) u32 u32x4;

__device__ inline floatx4 mfma16(short8 a, short8 b, floatx4 c) {
  return __builtin_amdgcn_mfma_f32_16x16x32_bf16(a, b, c, 0, 0, 0);
}
__device__ inline f32x16 mfma32(short8 a, short8 b, f32x16 c) {
  return __builtin_amdgcn_mfma_f32_32x32x16_bf16(a, b, c, 0, 0, 0);
}

__device__ inline u16 f2bf(float f) {
  __hip_bfloat16 h = __float2bfloat16(f);   // RNE
  return __builtin_bit_cast(u16, h);
}
__device__ inline u32 pack2bf(float lo, float hi) {
  return (u32)f2bf(lo) | ((u32)f2bf(hi) << 16);
}

// async global -> LDS, 16B per lane; dest = uniform base + lane*16
__device__ inline void gload16(const void* g, void* s) {
  __builtin_amdgcn_global_load_lds(
      (const __attribute__((address_space(1))) void*)g,
      (__attribute__((address_space(3))) void*)s, 16, 0, 0);
}

// ---------------------------------------------------------------- fused casts
__global__ void cast_all_kernel(const float* __restrict__ x,
                                const float* __restrict__ Wq, const float* __restrict__ Wk,
                                const float* __restrict__ Wv, const float* __restrict__ Wo,
                                u16* __restrict__ Xb, u16* __restrict__ Wqb, u16* __restrict__ Wkb,
                                u16* __restrict__ Wvb, u16* __restrict__ Wob) {
  size_t i4 = ((size_t)blockIdx.x * 256 + threadIdx.x) * 4;
  size_t seg = i4 >> 20;
  const float* src; u16* dst; size_t off;
  if (seg < 4)       { src = x;  dst = Xb;  off = i4; }
  else if (seg == 4) { src = Wq; dst = Wqb; off = i4 - ((size_t)4 << 20); }
  else if (seg == 5) { src = Wk; dst = Wkb; off = i4 - ((size_t)5 << 20); }
  else if (seg == 6) { src = Wv; dst = Wvb; off = i4 - ((size_t)6 << 20); }
  else               { src = Wo; dst = Wob; off = i4 - ((size_t)7 << 20); }
  float4 v = *(const float4*)(src + off);
  ushort4 o;
  o.x = f2bf(v.x); o.y = f2bf(v.y); o.z = f2bf(v.z); o.w = f2bf(v.w);
  *(ushort4*)(dst + off) = o;
}

// ---------------------------------------------------------------- rope table
__global__ void rope_table_kernel(float* __restrict__ cosT, float* __restrict__ sinT) {
  int tid = blockIdx.x * blockDim.x + threadIdx.x;   // T*32
  int t = tid >> 5, j = tid & 31;
  double inv = pow(10000.0, -((double)(2 * j) / 64.0));
  double a = (double)t * inv;
  cosT[tid] = (float)cos(a);
  sinT[tid] = (float)sin(a);
}

// ---------------------------------------------------------------- GEMM: C[M,N] = A[M,K] * W[N,K]^T + bias
// 128x128 tile, BK=32, double-buffered LDS via global_load_lds(16B), 4 waves (2x2).
// DO_ROPE: z<2 -> fused RoPE epilogue (Q,K); z==2 -> V^T epilogue (writes [B,H,64,T]).
template<int OUT_BF16, int DO_ROPE>
__global__ __launch_bounds__(256) void gemm128_kernel(
    const u16* __restrict__ A,
    const u16* __restrict__ W0, const u16* __restrict__ W1, const u16* __restrict__ W2,
    const float* __restrict__ b0, const float* __restrict__ b1, const float* __restrict__ b2,
    void* __restrict__ C0, void* __restrict__ C1, void* __restrict__ C2,
    const float* __restrict__ cosT, const float* __restrict__ sinT) {
  const int z = blockIdx.z;
  const u16*  W    = (z == 0) ? W0 : (z == 1 ? W1 : W2);
  const float* bias = (z == 0) ? b0 : (z == 1 ? b1 : b2);
  void*       C    = (z == 0) ? C0 : (z == 1 ? C1 : C2);
  const int K = D_MOD, N = D_MOD;

  __shared__ __align__(16) char smem[34816];
  u16* lA0 = (u16*)smem;                 // [128*32]
  u16* lA1 = (u16*)(smem + 8192);
  u16* lB0 = (u16*)(smem + 16384);
  u16* lB1 = (u16*)(smem + 24576);

  const int tid = threadIdx.x;
  const int w = tid >> 6, l = tid & 63, g = l >> 4, ln = l & 15;
  const int wr = w >> 1, wc = w & 1;
  const int m0 = blockIdx.y * 128, n0 = blockIdx.x * 128;

  floatx4 acc[4][4];
#pragma unroll
  for (int mi = 0; mi < 4; ++mi)
#pragma unroll
    for (int ni = 0; ni < 4; ++ni) acc[mi][ni] = (floatx4){0.f, 0.f, 0.f, 0.f};

  auto stage = [&](u16* la, u16* lb, int kk) {
#pragma unroll
    for (int p = 0; p < 2; ++p) {
      int c = p * 256 + w * 64 + l;
      int r = c >> 2, cc = c & 3;
      gload16(A + (size_t)(m0 + r) * K + kk + cc * 8, la + (p * 256 + w * 64) * 8);
      gload16(W + (size_t)(n0 + r) * K + kk + cc * 8, lb + (p * 256 + w * 64) * 8);
    }
  };

  stage(lA0, lB0, 0);
  __syncthreads();
  for (int t = 0; t < K / 32; ++t) {
    u16* la = (t & 1) ? lA1 : lA0;
    u16* lb = (t & 1) ? lB1 : lB0;
    if (t + 1 < K / 32) stage((t & 1) ? lA0 : lA1, (t & 1) ? lB0 : lB1, (t + 1) * 32);
    short8 af[4], bf[4];
#pragma unroll
    for (int mi = 0; mi < 4; ++mi)
      af[mi] = *(const short8*)&la[(wr * 64 + mi * 16 + ln) * 32 + g * 8];
#pragma unroll
    for (int ni = 0; ni < 4; ++ni)
      bf[ni] = *(const short8*)&lb[(wc * 64 + ni * 16 + ln) * 32 + g * 8];
#pragma unroll
    for (int mi = 0; mi < 4; ++mi)
#pragma unroll
      for (int ni = 0; ni < 4; ++ni)
        acc[mi][ni] = mfma16(af[mi], bf[ni], acc[mi][ni]);
    __syncthreads();
  }

  float bv[4];
#pragma unroll
  for (int ni = 0; ni < 4; ++ni) bv[ni] = bias[n0 + wc * 64 + ni * 16 + ln];

  if (DO_ROPE && z == 2) {
    // ---- V^T epilogue: bounce C-tile through LDS, write Vt[B,H,64,T]
    u16* pt = (u16*)smem;   // [128][136] u16
#pragma unroll
    for (int mi = 0; mi < 4; ++mi)
#pragma unroll
      for (int ni = 0; ni < 4; ++ni)
#pragma unroll
        for (int r = 0; r < 4; ++r)
          pt[(wc * 64 + ni * 16 + ln) * 136 + wr * 64 + mi * 16 + g * 4 + r] =
              f2bf(acc[mi][ni][r] + bv[ni]);
    __syncthreads();
    u16* Vt = (u16*)C;
    const int b = m0 >> 11, tc0 = m0 & (T_SEQ - 1);
#pragma unroll
    for (int i = 0; i < 8; ++i) {
      const int c = tid + 256 * i;
      const int row = c >> 4, mc = c & 15;
      const int n = n0 + row;
      const int hh = n >> 6, d = n & 63;
      short8 val = *(const short8*)&pt[row * 136 + mc * 8];
      *(short8*)(Vt + ((size_t)(b * N_HEADS + hh) * 64 + d) * T_SEQ + tc0 + mc * 8) = val;
    }
    return;
  }

#pragma unroll
  for (int mi = 0; mi < 4; ++mi) {
#pragma unroll
    for (int r = 0; r < 4; ++r) {
      const int m = m0 + wr * 64 + mi * 16 + g * 4 + r;
      if (DO_ROPE && z < 2) {
        const int t = m & (T_SEQ - 1);
#pragma unroll
        for (int ni = 0; ni < 2; ++ni) {
          const int j = ni * 16 + ln;
          float cv = cosT[t * 32 + j], sv = sinT[t * 32 + j];
          float v1 = acc[mi][ni][r] + bv[ni];
          float v2 = acc[mi][ni + 2][r] + bv[ni + 2];
          ((u16*)C)[(size_t)m * N + n0 + wc * 64 + j]      = f2bf(v1 * cv - v2 * sv);
          ((u16*)C)[(size_t)m * N + n0 + wc * 64 + j + 32] = f2bf(v1 * sv + v2 * cv);
        }
      } else {
#pragma unroll
        for (int ni = 0; ni < 4; ++ni) {
          float v = acc[mi][ni][r] + bv[ni];
          size_t idx = (size_t)m * N + n0 + wc * 64 + ni * 16 + ln;
          if (OUT_BF16) ((u16*)C)[idx] = f2bf(v);
          else          ((float*)C)[idx] = v;
        }
      }
    }
  }
}

// ---------------------------------------------------------------- flash attention v5 (causal)
// 32x32x16 MFMA, swapped operands: S^T = K·Q^T (lane owns one q-col, 32 kv rows in regs),
// O^T = V^T·P^T (lane keeps same q-col -> scalar m/l/alpha). In-register softmax.
// Cross-lane only via __shfl_xor(.,32). No LDS, no barriers. 1 wave = 32 q-rows.
__global__ __launch_bounds__(256) void flash5_kernel(const u16* __restrict__ Q, const u16* __restrict__ Kb,
                                                     const u16* __restrict__ Vt, u16* __restrict__ O) {
  const int tid = threadIdx.x;
  const int w = tid >> 6, l = tid & 63;
  const int lq = l & 31, hi = l >> 5;

  // XCD-clustered: 64 consecutive wgs per XCD -> 4 bh per XCD (K+Vt ~2MB in 4MB L2)
  const int orig = blockIdx.x;                    // 0..511
  const int wg = (orig & 7) * 64 + (orig >> 3);
  const int bh = wg >> 4;                         // 0..31
  const int qg = wg & 15;                         // 0..15
  // balanced causal work: qt sums equal per block
  const int qt = (w == 0) ? qg : (w == 1) ? 63 - qg : (w == 2) ? 31 - qg : 32 + qg;
  const int q0 = qt * 32;
  const int b = bh >> 4, h = bh & 15;

  const u16* Qh = Q  + (size_t)b * T_SEQ * D_MOD + h * HEAD_DIM;
  const u16* Kh = Kb + (size_t)b * T_SEQ * D_MOD + h * HEAD_DIM;
  const u16* Vh = Vt + (size_t)bh * 64 * T_SEQ;   // rows d, stride T_SEQ

  // Q fragments (B-operand: col = q0+lq, k-elems d = 16j + 8hi + 0..7)
  short8 qf[4];
  {
    const u16* qp = Qh + (size_t)(q0 + lq) * D_MOD + 8 * hi;
#pragma unroll
    for (int j = 0; j < 4; ++j) qf[j] = *(const short8*)(qp + 16 * j);
  }

  f32x16 o0, o1;
#pragma unroll
  for (int r = 0; r < 16; ++r) { o0[r] = 0.f; o1[r] = 0.f; }
  float m_r = -INFINITY, l_r = 0.f;

  const int ntiles = (qt >> 1) + 1;
  for (int kt = 0; kt < ntiles; ++kt) {
    const int k0 = kt * 64;
    const bool last = (kt == ntiles - 1);

    // ---- issue all 16 loads up-front (K for QK^T, V for PV)
    short8 kf0[4], kf1[4], vf0[4], vf1[4];
    {
      const u16* kp0 = Kh + (size_t)(k0 + lq) * D_MOD + 8 * hi;
      const u16* kp1 = kp0 + 32 * D_MOD;
#pragma unroll
      for (int j = 0; j < 4; ++j) {
        kf0[j] = *(const short8*)(kp0 + 16 * j);
        kf1[j] = *(const short8*)(kp1 + 16 * j);
      }
      const u16* vp0 = Vh + (size_t)lq * T_SEQ + k0 + 8 * hi;
      const u16* vp1 = vp0 + 32 * T_SEQ;
#pragma unroll
      for (int js = 0; js < 4; ++js) {
        vf0[js] = *(const short8*)(vp0 + 16 * js);
        vf1[js] = *(const short8*)(vp1 + 16 * js);
      }
    }

    // ---- S^T = K·Q^T  (two 32-row accs over kv)
    f32x16 s0, s1;
#pragma unroll
    for (int r = 0; r < 16; ++r) { s0[r] = 0.f; s1[r] = 0.f; }
    __builtin_amdgcn_s_setprio(1);
#pragma unroll
    for (int j = 0; j < 4; ++j) {
      s0 = mfma32(kf0[j], qf[j], s0);
      s1 = mfma32(kf1[j], qf[j], s1);
    }
    __builtin_amdgcn_s_setprio(0);

    // ---- scale + causal mask (kv = k0 + 32a + (r&3)+8*(r>>2)+4hi; q = q0+lq)
    float p[32];
#pragma unroll
    for (int r = 0; r < 16; ++r) { p[r] = s0[r] * 0.125f; p[16 + r] = s1[r] * 0.125f; }
    if (last) {
      const int qrow = q0 + lq;
#pragma unroll
      for (int r = 0; r < 16; ++r) {
        const int kv = k0 + (r & 3) + 8 * (r >> 2) + 4 * hi;
        if (kv > qrow) p[r] = -10000.0f;
        if (kv + 32 > qrow) p[16 + r] = -10000.0f;
      }
    }

    // ---- online softmax: local tree + cross-half shfl
    float mx = p[0];
#pragma unroll
    for (int i = 1; i < 32; ++i) mx = fmaxf(mx, p[i]);
    mx = fmaxf(mx, __shfl_xor(mx, 32));

    const float mnew = fmaxf(m_r, mx);
    const float alpha = __expf(m_r - mnew);   // first tile: exp(-inf)=0
    l_r *= alpha;
#pragma unroll
    for (int r = 0; r < 16; ++r) { o0[r] *= alpha; o1[r] *= alpha; }
    m_r = mnew;
#pragma unroll
    for (int i = 0; i < 32; ++i) p[i] = __expf(p[i] - m_r);
    float sum = 0.f;
#pragma unroll
    for (int i = 0; i < 32; ++i) sum += p[i];
    sum += __shfl_xor(sum, 32);
    l_r += sum;

    // ---- P^T fragments: pack pairs to bf16 words, exchange across lane-halves
    u32x4 fw[4];
#pragma unroll
    for (int a = 0; a < 2; ++a) {
      u32 W[8];
#pragma unroll
      for (int j = 0; j < 8; ++j) W[j] = pack2bf(p[16 * a + 2 * j], p[16 * a + 2 * j + 1]);
      // hi=0 needs partner's W0,W1 (for w2,w3); hi=1 needs partner's W2,W3 (for w0,w1)
      u32 A0 = __shfl_xor(hi ? W[0] : W[2], 32);
      u32 A1 = __shfl_xor(hi ? W[1] : W[3], 32);
      u32 B0 = __shfl_xor(hi ? W[4] : W[6], 32);
      u32 B1 = __shfl_xor(hi ? W[5] : W[7], 32);
      fw[2 * a]     = (u32x4){hi ? A0 : W[0], hi ? A1 : W[1], hi ? W[2] : A0, hi ? W[3] : A1};
      fw[2 * a + 1] = (u32x4){hi ? B0 : W[4], hi ? B1 : W[5], hi ? W[6] : B0, hi ? W[7] : B1};
    }

    // ---- O^T += V^T · P^T
    __builtin_amdgcn_s_setprio(1);
#pragma unroll
    for (int js = 0; js < 4; ++js) {
      short8 pf = __builtin_bit_cast(short8, fw[js]);
      o0 = mfma32(vf0[js], pf, o0);
      o1 = mfma32(vf1[js], pf, o1);
    }
    __builtin_amdgcn_s_setprio(0);
  }

  // ---- epilogue: per-lane scalar 1/l, write O[b][q][h*64+d]
  const float inv = 1.0f / l_r;
  u16* op = O + (size_t)b * T_SEQ * D_MOD + (size_t)(q0 + lq) * D_MOD + h * HEAD_DIM;
#pragma unroll
  for (int a = 0; a < 2; ++a) {
#pragma unroll
    for (int rq = 0; rq < 4; ++rq) {
      const int d0 = 32 * a + 8 * rq + 4 * hi;
      ushort4 st;
      st.x = f2bf(((a == 0) ? o0[4 * rq + 0] : o1[4 * rq + 0]) * inv);
      st.y = f2bf(((a == 0) ? o0[4 * rq + 1] : o1[4 * rq + 1]) * inv);
      st.z = f2bf(((a == 0) ? o0[4 * rq + 2] : o1[4 * rq + 2]) * inv);
      st.w = f2bf(((a == 0) ? o0[4 * rq + 3] : o1[4 * rq + 3]) * inv);
      *(ushort4*)(op + d0) = st;
    }
  }
}

// ---------------------------------------------------------------- launch
extern "C" void kernel_launch(void* const* d_in, const int* in_sizes, int n_in,
                              void* d_out, int out_size, void* d_ws, size_t ws_size,
                              hipStream_t stream) {
  const float* x  = (const float*)d_in[0];
  const float* Wq = (const float*)d_in[2];
  const float* bq = (const float*)d_in[3];
  const float* Wk = (const float*)d_in[4];
  const float* bk = (const float*)d_in[5];
  const float* Wv = (const float*)d_in[6];
  const float* bv = (const float*)d_in[7];
  const float* Wo = (const float*)d_in[8];
  const float* bo = (const float*)d_in[9];
  float* out = (float*)d_out;

  char* ws = (char*)d_ws;
  const size_t MB = 1024 * 1024;
  u16* Xb   = (u16*)(ws + 0);          // 8 MB; dead after QKV gemm -> Ab reuses it
  u16* Ab   = (u16*)(ws + 0);
  u16* Wqb  = (u16*)(ws + 8 * MB);
  u16* Wkb  = (u16*)(ws + 10 * MB);
  u16* Wvb  = (u16*)(ws + 12 * MB);
  u16* Wob  = (u16*)(ws + 14 * MB);
  u16* Qb   = (u16*)(ws + 16 * MB);    // 8 MB
  u16* Kb   = (u16*)(ws + 24 * MB);    // 8 MB
  u16* Vt   = (u16*)(ws + 32 * MB);    // 16 MB  [B,H,64,T]
  float* cosT = (float*)(ws + 48 * MB);          // 256 KB
  float* sinT = (float*)(ws + 48 * MB + 256 * 1024);

  cast_all_kernel<<<8192, 256, 0, stream>>>(x, Wq, Wk, Wv, Wo, Xb, Wqb, Wkb, Wvb, Wob);
  rope_table_kernel<<<256, 256, 0, stream>>>(cosT, sinT);

  gemm128_kernel<1, 1><<<dim3(8, 32, 3), 256, 0, stream>>>(
      Xb, Wqb, Wkb, Wvb, bq, bk, bv, Qb, Kb, Vt, cosT, sinT);

  flash5_kernel<<<dim3(512), 256, 0, stream>>>(Qb, Kb, Vt, Ab);

  gemm128_kernel<0, 0><<<dim3(8, 32, 1), 256, 0, stream>>>(
      Ab, Wob, Wob, Wob, bo, bo, bo, out, out, out, nullptr, nullptr);
}